// Round 1
// baseline (562.656 us; speedup 1.0000x reference)
//
#include <hip/hip_runtime.h>

// BiLSTM fused kernel for MI355X (gfx950).
// B=4096, T=256, D=20, E=64, H=16, 4H=64, head: 32->64->16->2.
// One wave per batch sequence; lane j owns gate/unit output j in [0,64).
// Only truly sequential work per step: h(16) @ Wfh(16x64). The x-projection and
// xh@Wfx are computed inline per step from register-resident weight columns.
// bwd LSTM output at t=T-1 is a single step from zero state (reverse-scan
// semantics), so no second scan is needed.

#define TC 64  // timesteps staged in LDS per refill (TC*20 floats per wave)

__device__ __forceinline__ float tanh_fast(float x) {
    // tanh(x) = 2*sigmoid(2x)-1 = 2/(1+exp(-2x)) - 1 ; saturates cleanly via inf
    float e = __expf(-2.f * x);
    return __fdividef(2.f, 1.f + e) - 1.f;
}

__global__ __launch_bounds__(256, 3)
void bilstm_fused(const float* __restrict__ x,
                  const float* __restrict__ W0, const float* __restrict__ b0,
                  const float* __restrict__ Wf, const float* __restrict__ bf,
                  const float* __restrict__ Wb, const float* __restrict__ bb,
                  const float* __restrict__ W1, const float* __restrict__ b1,
                  const float* __restrict__ W2, const float* __restrict__ b2,
                  const float* __restrict__ W3, const float* __restrict__ b3,
                  float* __restrict__ out)
{
    // wave-private LDS regions (no cross-wave sharing -> no __syncthreads anywhere)
    __shared__ __align__(16) float xbuf[4][TC * 20];  // staged x chunk per wave
    __shared__ __align__(16) float xh_sh[4][64];      // xh broadcast buffer
    __shared__ __align__(16) float h_sh[4][48];       // [0:16) h_fwd, [16:32) h_bwd, [32:48) l2

    const int wave = threadIdx.x >> 6;
    const int j    = threadIdx.x & 63;
    const int b    = (blockIdx.x << 2) + wave;        // grid = 1024 blocks -> b < 4096

    // ---- per-lane weight columns in registers (all loops touching these MUST fully unroll)
    float w0r[20], wfx[64], wfh[16];
#pragma unroll
    for (int k = 0; k < 20; ++k) w0r[k] = W0[k * 64 + j];
#pragma unroll
    for (int k = 0; k < 64; ++k) wfx[k] = Wf[k * 64 + j];
#pragma unroll
    for (int k = 0; k < 16; ++k) wfh[k] = Wf[(64 + k) * 64 + j];
    const float b0j = b0[j];
    const float bfj = bf[j];

    const int   quad  = j >> 4;                  // 0:i 1:g 2:f 3:o
    const int   jq    = j & 15;
    const float fbias = (quad == 2) ? 1.f : 0.f; // haiku forget-gate +1
    const bool  gsel  = (quad == 1);             // tanh for g-gate

    float c = 0.f;
    if (j < 16) h_sh[wave][j] = 0.f;
    __builtin_amdgcn_wave_barrier();

    const float* xb = x + (size_t)b * (256 * 20);

#pragma unroll 1
    for (int t0 = 0; t0 < 256; t0 += TC) {
        // stage TC*20 floats = 320 float4 for this wave's batch (coalesced 16B loads)
        const float4* src = (const float4*)(xb + t0 * 20);
        float4*       dst = (float4*)xbuf[wave];
#pragma unroll
        for (int i = 0; i < (TC * 20 / 4) / 64; ++i)
            dst[j + i * 64] = src[j + i * 64];
        __builtin_amdgcn_wave_barrier();

#pragma unroll 1
        for (int tt = 0; tt < TC; ++tt) {
            // ---- xh_j = relu(x_t @ W0 + b0)[j] : 5 ds_read_b128 broadcasts + 20 FMA
            const float* xp = &xbuf[wave][tt * 20];
            float4 xv[5];
#pragma unroll
            for (int i = 0; i < 5; ++i) xv[i] = ((const float4*)xp)[i];
            float a0 = b0j, a1 = 0.f, a2 = 0.f, a3 = 0.f;
#pragma unroll
            for (int i = 0; i < 5; ++i) {
                a0 = fmaf(xv[i].x, w0r[4 * i + 0], a0);
                a1 = fmaf(xv[i].y, w0r[4 * i + 1], a1);
                a2 = fmaf(xv[i].z, w0r[4 * i + 2], a2);
                a3 = fmaf(xv[i].w, w0r[4 * i + 3], a3);
            }
            float xh = fmaxf((a0 + a1) + (a2 + a3), 0.f);
            xh_sh[wave][j] = xh;
            __builtin_amdgcn_wave_barrier();

            // ---- gated_j = bf_j + h @ Wfh[:,j] + xh @ Wfx[:,j]
            float u0 = bfj, u1 = 0.f, u2 = 0.f, u3 = 0.f;
            const float4* hs = (const float4*)h_sh[wave];   // h_{t-1}, read BEFORE write below
#pragma unroll
            for (int k4 = 0; k4 < 4; ++k4) {
                float4 v = hs[k4];
                u0 = fmaf(v.x, wfh[4 * k4 + 0], u0);
                u1 = fmaf(v.y, wfh[4 * k4 + 1], u1);
                u2 = fmaf(v.z, wfh[4 * k4 + 2], u2);
                u3 = fmaf(v.w, wfh[4 * k4 + 3], u3);
            }
            const float4* xs = (const float4*)xh_sh[wave];  // 16 ds_read_b128 broadcasts
#pragma unroll
            for (int k4 = 0; k4 < 16; ++k4) {
                float4 v = xs[k4];
                u0 = fmaf(v.x, wfx[4 * k4 + 0], u0);
                u1 = fmaf(v.y, wfx[4 * k4 + 1], u1);
                u2 = fmaf(v.z, wfx[4 * k4 + 2], u2);
                u3 = fmaf(v.w, wfx[4 * k4 + 3], u3);
            }
            float gated = (u0 + u1) + (u2 + u3);

            // ---- gate nonlinearity (uniform per lane-quad): sigmoid or tanh via one exp
            float e = __expf((gsel ? -2.f : -1.f) * (gated + fbias));
            float y = __fdividef(1.f, 1.f + e);
            float a = gsel ? (2.f * y - 1.f) : y;

            // ---- gather i/g/f/o for unit jq; every lane computes identical c (bounded, no NaN)
            float ai = __shfl(a, jq, 64);
            float ag = __shfl(a, jq + 16, 64);
            float af = __shfl(a, jq + 32, 64);
            float ao = __shfl(a, jq + 48, 64);
            c = fmaf(af, c, ai * ag);
            float hnew = ao * tanh_fast(c);
            __builtin_amdgcn_wave_barrier();
            if (j < 16) h_sh[wave][j] = hnew;     // h_t for next step
            __builtin_amdgcn_wave_barrier();
        }
    }

    // ---- backward LSTM: single step from zero state on xh_{T-1} (still in xh_sh).
    // c_prev = 0 -> forget-gate term vanishes; gated_b = xh @ Wbx + bb.
    {
        float u0 = bb[j], u1 = 0.f, u2 = 0.f, u3 = 0.f;
        const float4* xs = (const float4*)xh_sh[wave];
#pragma unroll
        for (int k4 = 0; k4 < 16; ++k4) {
            float4 v = xs[k4];
            u0 = fmaf(v.x, Wb[(4 * k4 + 0) * 64 + j], u0);
            u1 = fmaf(v.y, Wb[(4 * k4 + 1) * 64 + j], u1);
            u2 = fmaf(v.z, Wb[(4 * k4 + 2) * 64 + j], u2);
            u3 = fmaf(v.w, Wb[(4 * k4 + 3) * 64 + j], u3);
        }
        float gated = (u0 + u1) + (u2 + u3);
        float e = __expf((gsel ? -2.f : -1.f) * gated);   // f-gate value irrelevant (c_prev=0)
        float y = __fdividef(1.f, 1.f + e);
        float a = gsel ? (2.f * y - 1.f) : y;
        float ai = __shfl(a, jq, 64);
        float ag = __shfl(a, jq + 16, 64);
        float ao = __shfl(a, jq + 48, 64);
        float cb = ai * ag;
        float hb = ao * tanh_fast(cb);
        __builtin_amdgcn_wave_barrier();
        if (j < 16) h_sh[wave][16 + j] = hb;
        __builtin_amdgcn_wave_barrier();
    }

    // ---- head MLP: l1 = relu([hf,hb] @ W1 + b1)  (lane j computes output j of 64)
    {
        float u0 = b1[j], u1 = 0.f, u2 = 0.f, u3 = 0.f;
        const float4* hs = (const float4*)h_sh[wave];     // 32 floats: hf ++ hb
#pragma unroll
        for (int k4 = 0; k4 < 8; ++k4) {
            float4 v = hs[k4];
            u0 = fmaf(v.x, W1[(4 * k4 + 0) * 64 + j], u0);
            u1 = fmaf(v.y, W1[(4 * k4 + 1) * 64 + j], u1);
            u2 = fmaf(v.z, W1[(4 * k4 + 2) * 64 + j], u2);
            u3 = fmaf(v.w, W1[(4 * k4 + 3) * 64 + j], u3);
        }
        float l1 = fmaxf((u0 + u1) + (u2 + u3), 0.f);
        __builtin_amdgcn_wave_barrier();
        xh_sh[wave][j] = l1;                              // reuse as l1 broadcast buffer
        __builtin_amdgcn_wave_barrier();

        // l2 = relu(l1 @ W2 + b2), 16 outputs on lanes 0..15
        if (j < 16) {
            float v0 = b2[j], v1 = 0.f, v2 = 0.f, v3 = 0.f;
            const float4* ls = (const float4*)xh_sh[wave];
#pragma unroll
            for (int k4 = 0; k4 < 16; ++k4) {
                float4 v = ls[k4];
                v0 = fmaf(v.x, W2[(4 * k4 + 0) * 16 + j], v0);
                v1 = fmaf(v.y, W2[(4 * k4 + 1) * 16 + j], v1);
                v2 = fmaf(v.z, W2[(4 * k4 + 2) * 16 + j], v2);
                v3 = fmaf(v.w, W2[(4 * k4 + 3) * 16 + j], v3);
            }
            h_sh[wave][32 + j] = fmaxf((v0 + v1) + (v2 + v3), 0.f);
        }
        __builtin_amdgcn_wave_barrier();

        // out = l2 @ W3 + b3, 2 outputs on lanes 0..1
        if (j < 2) {
            float o = b3[j];
#pragma unroll
            for (int k = 0; k < 16; ++k)
                o = fmaf(h_sh[wave][32 + k], W3[k * 2 + j], o);
            out[b * 2 + j] = o;
        }
    }
}

extern "C" void kernel_launch(void* const* d_in, const int* in_sizes, int n_in,
                              void* d_out, int out_size, void* d_ws, size_t ws_size,
                              hipStream_t stream) {
    const float* x  = (const float*)d_in[0];
    const float* W0 = (const float*)d_in[1];
    const float* b0 = (const float*)d_in[2];
    const float* Wf = (const float*)d_in[3];
    const float* bf = (const float*)d_in[4];
    const float* Wb = (const float*)d_in[5];
    const float* bb = (const float*)d_in[6];
    const float* W1 = (const float*)d_in[7];
    const float* b1 = (const float*)d_in[8];
    const float* W2 = (const float*)d_in[9];
    const float* b2 = (const float*)d_in[10];
    const float* W3 = (const float*)d_in[11];
    const float* b3 = (const float*)d_in[12];
    float* outp = (float*)d_out;

    hipLaunchKernelGGL(bilstm_fused, dim3(4096 / 4), dim3(256), 0, stream,
                       x, W0, b0, Wf, bf, Wb, bb, W1, b1, W2, b2, W3, b3, outp);
}

// Round 2
// 427.990 us; speedup vs baseline: 1.3146x; 1.3146x over previous
//
#include <hip/hip_runtime.h>

// BiLSTM fused kernel for MI355X (gfx950) — round 2: LDS-free recurrent loop.
// B=4096, T=256, D=20, E=64, H=16, 4H=64, head: 32->64->16->2.
// One wave per sequence; lane j owns gate column j. All matvec cross-lane
// traffic via DPP row_ror fmacs (register crossbar); h state needs NO
// communication (lane j holds h[j&15]); xh needs 3 shfl_xor row copies.
// x_t read straight from global (lane-uniform addr -> 1 coalesced line),
// prefetched one step ahead. LDS used only in the one-time epilogue.

__device__ __forceinline__ float tanh_fast(float x) {
    float e = __expf(-2.f * x);
    return __fdividef(2.f, 1.f + e) - 1.f;
}

// 5 rotated fmacs per rotation distance S: 4 xh row-copies + 1 h (within-row).
// DPP on src0 only; accumulator chains carry the dependency.
#define FMAC5(S)                                                                          \
  asm volatile("v_fmac_f32 %0, %1, %2 row_ror:" #S : "+v"(u0) : "v"(c0), "v"(wfxp[S]));      \
  asm volatile("v_fmac_f32 %0, %1, %2 row_ror:" #S : "+v"(u1) : "v"(c1), "v"(wfxp[16 + S])); \
  asm volatile("v_fmac_f32 %0, %1, %2 row_ror:" #S : "+v"(u2) : "v"(c2), "v"(wfxp[32 + S])); \
  asm volatile("v_fmac_f32 %0, %1, %2 row_ror:" #S : "+v"(u3) : "v"(c3), "v"(wfxp[48 + S])); \
  asm volatile("v_fmac_f32 %0, %1, %2 row_ror:" #S : "+v"(v0) : "v"(hh), "v"(wfhp[S]));

__global__ __launch_bounds__(256, 3)
void bilstm_fused(const float* __restrict__ x,
                  const float* __restrict__ W0, const float* __restrict__ b0,
                  const float* __restrict__ Wf, const float* __restrict__ bf,
                  const float* __restrict__ Wb, const float* __restrict__ bb,
                  const float* __restrict__ W1, const float* __restrict__ b1,
                  const float* __restrict__ W2, const float* __restrict__ b2,
                  const float* __restrict__ W3, const float* __restrict__ b3,
                  float* __restrict__ out)
{
    __shared__ __align__(16) float xh_sh[4][64];  // epilogue only
    __shared__ __align__(16) float h_sh[4][48];   // [0:16) hf, [16:32) hb, [32:48) l2

    const int wave = threadIdx.x >> 6;
    const int j    = threadIdx.x & 63;
    const int b    = (blockIdx.x << 2) + wave;
    const int r    = j >> 4;   // quad == row-of-16 index
    const int jq   = j & 15;

    // ---- runtime probe of row_ror source direction (hedges ISA ambiguity):
    // if lane i receives lane (i+1)'s value under row_ror:1, plus==true.
    int rot1 = __builtin_amdgcn_mov_dpp(j, 0x121 /*row_ror:1*/, 0xf, 0xf, false);
    const bool plus = ((rot1 & 15) == ((jq + 1) & 15));

    // ---- register-resident weights, permuted to match the rotation schedule.
    // At iter s, copy m holds xh[16*(r^m) + srcq(s)]; weight must be
    // Wf[(16*(r^m) + srcq(s))*64 + j].
    float w0r[20], wfxp[64], wfhp[16];
#pragma unroll
    for (int k = 0; k < 20; ++k) w0r[k] = W0[k * 64 + j];
#pragma unroll
    for (int s = 0; s < 16; ++s) {
        const int srcq = plus ? ((jq + s) & 15) : ((jq + 16 - s) & 15);
        wfhp[s] = Wf[(64 + srcq) * 64 + j];
#pragma unroll
        for (int m = 0; m < 4; ++m)
            wfxp[m * 16 + s] = Wf[(16 * (r ^ m) + srcq) * 64 + j];
    }
    const float b0j = b0[j];
    const float bfj = bf[j];

    const float gmul  = (r == 1) ? -2.f : -1.f;  // tanh for g-gate via exp(-2x)
    const float gbias = (r == 2) ? 1.f : 0.f;    // haiku forget-gate +1
    const float amul  = (r == 1) ? 2.f : 1.f;
    const float aadd  = (r == 1) ? -1.f : 0.f;
    const bool  b0sel = (r & 1) != 0;
    const bool  b1sel = (r & 2) != 0;

    float c = 0.f, hh = 0.f, xh_last = 0.f;
    const float* xb = x + (size_t)b * (256 * 20);

    // preload x_0 (lane-uniform address: one line per load)
    float4 xv[5];
    {
        const float4* xr = (const float4*)xb;
#pragma unroll
        for (int i = 0; i < 5; ++i) xv[i] = xr[i];
    }

#pragma unroll 1
    for (int t = 0; t < 256; ++t) {
        // ---- xh_j = relu(x_t @ W0 + b0)[j] : 20 FMA, 4-way ILP
        float a0 = b0j, a1 = 0.f, a2 = 0.f, a3 = 0.f;
#pragma unroll
        for (int i = 0; i < 5; ++i) {
            a0 = fmaf(xv[i].x, w0r[4 * i + 0], a0);
            a1 = fmaf(xv[i].y, w0r[4 * i + 1], a1);
            a2 = fmaf(xv[i].z, w0r[4 * i + 2], a2);
            a3 = fmaf(xv[i].w, w0r[4 * i + 3], a3);
        }
        float xh = fmaxf((a0 + a1) + (a2 + a3), 0.f);

        // ---- prefetch x_{t+1} into the now-dead xv registers (async, used next iter)
        {
            int tn = (t < 255) ? (t + 1) : 255;
            const float4* xr = (const float4*)(xb + tn * 20);
#pragma unroll
            for (int i = 0; i < 5; ++i) xv[i] = xr[i];
        }

        // ---- row copies of xh: copy m holds row (r^m)'s values
        float c0 = xh;
        float c1 = __shfl_xor(xh, 16);
        float c2 = __shfl_xor(xh, 32);
        float c3 = __shfl_xor(xh, 48);

        // ---- gated_j = bf_j + xh@Wfx[:,j] + h@Wfh[:,j], rotation distance s=0..15
        float u0 = fmaf(c0, wfxp[0], bfj);
        float u1 = c1 * wfxp[16];
        float u2 = c2 * wfxp[32];
        float u3 = c3 * wfxp[48];
        float v0 = hh * wfhp[0];
        asm volatile("s_nop 1");  // VALU-write -> DPP-read hazard (2 wait states)
        FMAC5(1)  FMAC5(2)  FMAC5(3)  FMAC5(4)  FMAC5(5)
        FMAC5(6)  FMAC5(7)  FMAC5(8)  FMAC5(9)  FMAC5(10)
        FMAC5(11) FMAC5(12) FMAC5(13) FMAC5(14) FMAC5(15)
        float gated = ((u0 + u1) + (u2 + u3)) + v0;

        // ---- per-quad activation: sigmoid, or tanh on g-quad; +1 on f-quad
        float e = __expf(gmul * (gated + gbias));
        float y = __fdividef(1.f, 1.f + e);
        float a = fmaf(y, amul, aadd);

        // ---- gather i/g/f/o of unit jq: xor-exchange + quad-bit mux (no LDS gather)
        float d1 = __shfl_xor(a, 16);
        float d2 = __shfl_xor(a, 32);
        float d3 = __shfl_xor(a, 48);
        float lo  = b0sel ? d1 : a;
        float hi  = b0sel ? d3 : d2;
        float lo1 = b0sel ? a  : d1;
        float hi1 = b0sel ? d2 : d3;
        float ai = b1sel ? hi  : lo;
        float ag = b1sel ? hi1 : lo1;
        float af = b1sel ? lo  : hi;
        float ao = b1sel ? lo1 : hi1;

        c  = fmaf(af, c, ai * ag);
        hh = ao * tanh_fast(c);   // lane j holds h_t[jq] — no communication needed
        xh_last = xh;
    }

    // ================= one-time epilogue (LDS fine here) =================
    xh_sh[wave][j] = xh_last;
    if (j < 16) h_sh[wave][j] = hh;
    __builtin_amdgcn_wave_barrier();

    // ---- backward LSTM output at t=T-1: one step from zero state on xh_{T-1}
    {
        float u0 = bb[j], u1 = 0.f, u2 = 0.f, u3 = 0.f;
        const float4* xs = (const float4*)xh_sh[wave];
#pragma unroll
        for (int k4 = 0; k4 < 16; ++k4) {
            float4 v = xs[k4];
            u0 = fmaf(v.x, Wb[(4 * k4 + 0) * 64 + j], u0);
            u1 = fmaf(v.y, Wb[(4 * k4 + 1) * 64 + j], u1);
            u2 = fmaf(v.z, Wb[(4 * k4 + 2) * 64 + j], u2);
            u3 = fmaf(v.w, Wb[(4 * k4 + 3) * 64 + j], u3);
        }
        float gated = (u0 + u1) + (u2 + u3);
        float e = __expf(gmul * gated);   // f-gate value irrelevant (c_prev=0)
        float y = __fdividef(1.f, 1.f + e);
        float a = fmaf(y, amul, aadd);
        float ai = __shfl(a, jq, 64);
        float ag = __shfl(a, jq + 16, 64);
        float ao = __shfl(a, jq + 48, 64);
        float cb = ai * ag;
        float hb = ao * tanh_fast(cb);
        __builtin_amdgcn_wave_barrier();
        if (j < 16) h_sh[wave][16 + j] = hb;
        __builtin_amdgcn_wave_barrier();
    }

    // ---- head MLP: l1 = relu([hf,hb] @ W1 + b1)
    {
        float u0 = b1[j], u1 = 0.f, u2 = 0.f, u3 = 0.f;
        const float4* hs = (const float4*)h_sh[wave];
#pragma unroll
        for (int k4 = 0; k4 < 8; ++k4) {
            float4 v = hs[k4];
            u0 = fmaf(v.x, W1[(4 * k4 + 0) * 64 + j], u0);
            u1 = fmaf(v.y, W1[(4 * k4 + 1) * 64 + j], u1);
            u2 = fmaf(v.z, W1[(4 * k4 + 2) * 64 + j], u2);
            u3 = fmaf(v.w, W1[(4 * k4 + 3) * 64 + j], u3);
        }
        float l1 = fmaxf((u0 + u1) + (u2 + u3), 0.f);
        __builtin_amdgcn_wave_barrier();
        xh_sh[wave][j] = l1;
        __builtin_amdgcn_wave_barrier();

        if (j < 16) {
            float v0 = b2[j], v1 = 0.f, v2 = 0.f, v3 = 0.f;
            const float4* ls = (const float4*)xh_sh[wave];
#pragma unroll
            for (int k4 = 0; k4 < 16; ++k4) {
                float4 v = ls[k4];
                v0 = fmaf(v.x, W2[(4 * k4 + 0) * 16 + j], v0);
                v1 = fmaf(v.y, W2[(4 * k4 + 1) * 16 + j], v1);
                v2 = fmaf(v.z, W2[(4 * k4 + 2) * 16 + j], v2);
                v3 = fmaf(v.w, W2[(4 * k4 + 3) * 16 + j], v3);
            }
            h_sh[wave][32 + j] = fmaxf((v0 + v1) + (v2 + v3), 0.f);
        }
        __builtin_amdgcn_wave_barrier();

        if (j < 2) {
            float o = b3[j];
#pragma unroll
            for (int k = 0; k < 16; ++k)
                o = fmaf(h_sh[wave][32 + k], W3[k * 2 + j], o);
            out[b * 2 + j] = o;
        }
    }
}

extern "C" void kernel_launch(void* const* d_in, const int* in_sizes, int n_in,
                              void* d_out, int out_size, void* d_ws, size_t ws_size,
                              hipStream_t stream) {
    const float* x  = (const float*)d_in[0];
    const float* W0 = (const float*)d_in[1];
    const float* b0 = (const float*)d_in[2];
    const float* Wf = (const float*)d_in[3];
    const float* bf = (const float*)d_in[4];
    const float* Wb = (const float*)d_in[5];
    const float* bb = (const float*)d_in[6];
    const float* W1 = (const float*)d_in[7];
    const float* b1 = (const float*)d_in[8];
    const float* W2 = (const float*)d_in[9];
    const float* b2 = (const float*)d_in[10];
    const float* W3 = (const float*)d_in[11];
    const float* b3 = (const float*)d_in[12];
    float* outp = (float*)d_out;

    hipLaunchKernelGGL(bilstm_fused, dim3(4096 / 4), dim3(256), 0, stream,
                       x, W0, b0, Wf, bf, Wb, bb, W1, b1, W2, b2, W3, b3, outp);
}